// Round 8
// baseline (276.114 us; speedup 1.0000x reference)
//
#include <hip/hip_runtime.h>
#include <math.h>

typedef __attribute__((ext_vector_type(8))) short bf16x8;
typedef __attribute__((ext_vector_type(4))) float f32x4;

constexpr int D = 256;           // feature dim (K of GEMM)
constexpr int H = 128;           // hidden dim
constexpr int KSTEPS = D / 32;   // 8 MFMA k-steps
constexpr int BM = 32;           // rows per block (2 row-groups x 16)

__device__ __forceinline__ float trunc_bf(float a) {
  return __uint_as_float(__float_as_uint(a) & 0xFFFF0000u);
}
__device__ __forceinline__ unsigned int pack2_bf(float a, float b) {
  return (__float_as_uint(a) >> 16) | (__float_as_uint(b) & 0xFFFF0000u);
}

union FragU { uint4 u; bf16x8 f; };

// ---- init: zero d_out + Z accumulator --------------------------------------
extern "C" __global__ void __launch_bounds__(256)
k_init(float* __restrict__ out, int out_size, float* __restrict__ zacc)
{
  const int i = blockIdx.x * 256 + threadIdx.x;
  if (i < out_size) out[i] = 0.0f;
  if (i == 0) *zacc = 0.0f;
}

// ---- Pre-pack W1 into per-lane MFMA B-fragment order (hi/lo bf16) ----------
// Index g = (kstep*8 + htile)*64 + lane; element j: K = kstep*32+(lane>>4)*8+j,
// N(col) = htile*16 + (lane&15).
extern "C" __global__ void __launch_bounds__(256)
k_pack(const float* __restrict__ W1, uint4* __restrict__ phi,
       uint4* __restrict__ plo)
{
  const int g = blockIdx.x * 256 + threadIdx.x;       // 0..4095
  const int c = g >> 9, ht = (g >> 6) & 7, l = g & 63;
  const int kbase = c * 32 + (l >> 4) * 8;
  const int col = ht * 16 + (l & 15);
  float v[8], lo[8];
#pragma unroll
  for (int i = 0; i < 8; ++i) {
    v[i] = W1[(size_t)(kbase + i) * H + col];
    lo[i] = v[i] - trunc_bf(v[i]);
  }
  uint4 h4, l4;
  h4.x = pack2_bf(v[0], v[1]); h4.y = pack2_bf(v[2], v[3]);
  h4.z = pack2_bf(v[4], v[5]); h4.w = pack2_bf(v[6], v[7]);
  l4.x = pack2_bf(lo[0], lo[1]); l4.y = pack2_bf(lo[2], lo[3]);
  l4.z = pack2_bf(lo[4], lo[5]); l4.w = pack2_bf(lo[6], lo[7]);
  phi[g] = h4; plo[g] = l4;
}

// ---- Fused: wave-independent MFMA scorer (zero-LDS phase 1) + pooling ------
// 4 waves as (rg,cg): wave handles rows rg*16..+15 x hidden cols cg*64..+63.
// All operands register-resident: x direct loads, B frags from L2 (packed).
// Issue-order discipline: per kstep issue ALL of (c+1)'s loads, compute c.
// N % 32 == 0 (300000 = 32*9375): no tail guards needed.
extern "C" __global__ void __launch_bounds__(256, 4)
k_fused3(const float* __restrict__ x, const int* __restrict__ batch,
         const uint4* __restrict__ phi, const uint4* __restrict__ plo,
         const float* __restrict__ b1, const float* __restrict__ W2,
         const float* __restrict__ b2, float* __restrict__ out,
         float* __restrict__ zacc, int N)
{
  __shared__ float sred[2][BM];   // per-col-half row partials
  __shared__ float wlds[BM];      // unnormalized weights

  const int t = threadIdx.x;
  const int l = t & 63;
  const int w = t >> 6;
  const int lg = l >> 4;          // k-group / C-row quad
  const int lr = l & 15;          // A M-row / B,C N-col
  const int rg = w >> 1;          // row group (0..1)
  const int cg = w & 1;           // col half (0..1)
  const int n0 = blockIdx.x * BM;

  const float* xrow = x + (size_t)(n0 + rg * 16 + lr) * D + lg * 8;

  f32x4 acc[4] = {};              // 4 local htiles
  FragU bhi[4], blo[4], nbhi[4], nblo[4];
  float4 xc0, xc1, nx0, nx1;

  // prologue: kstep 0 operands
#pragma unroll
  for (int h = 0; h < 4; ++h) {
    const int ht = cg * 4 + h;
    bhi[h].u = phi[ht * 64 + l];
    blo[h].u = plo[ht * 64 + l];
  }
  xc0 = *reinterpret_cast<const float4*>(xrow);
  xc1 = *reinterpret_cast<const float4*>(xrow + 4);

#pragma unroll 1
  for (int c = 0; c < KSTEPS; ++c) {
    // issue (c+1)'s loads first; nothing issued after them is needed earlier,
    // so the compiler's counted waitcnt for compute(c) drains nothing extra.
    if (c + 1 < KSTEPS) {
#pragma unroll
      for (int h = 0; h < 4; ++h) {
        const int ht = cg * 4 + h;
        nbhi[h].u = phi[((c + 1) * 8 + ht) * 64 + l];
        nblo[h].u = plo[((c + 1) * 8 + ht) * 64 + l];
      }
      nx0 = *reinterpret_cast<const float4*>(xrow + (c + 1) * 32);
      nx1 = *reinterpret_cast<const float4*>(xrow + (c + 1) * 32 + 4);
    }
    // pack current x into hi/lo fragments
    float v[8], lo[8];
    v[0] = xc0.x; v[1] = xc0.y; v[2] = xc0.z; v[3] = xc0.w;
    v[4] = xc1.x; v[5] = xc1.y; v[6] = xc1.z; v[7] = xc1.w;
#pragma unroll
    for (int i = 0; i < 8; ++i) lo[i] = v[i] - trunc_bf(v[i]);
    FragU ahi, alo;
    ahi.u.x = pack2_bf(v[0], v[1]);  ahi.u.y = pack2_bf(v[2], v[3]);
    ahi.u.z = pack2_bf(v[4], v[5]);  ahi.u.w = pack2_bf(v[6], v[7]);
    alo.u.x = pack2_bf(lo[0], lo[1]); alo.u.y = pack2_bf(lo[2], lo[3]);
    alo.u.z = pack2_bf(lo[4], lo[5]); alo.u.w = pack2_bf(lo[6], lo[7]);
#pragma unroll
    for (int h = 0; h < 4; ++h) {
      acc[h] = __builtin_amdgcn_mfma_f32_16x16x32_bf16(ahi.f, bhi[h].f, acc[h], 0, 0, 0);
      acc[h] = __builtin_amdgcn_mfma_f32_16x16x32_bf16(ahi.f, blo[h].f, acc[h], 0, 0, 0);
      acc[h] = __builtin_amdgcn_mfma_f32_16x16x32_bf16(alo.f, bhi[h].f, acc[h], 0, 0, 0);
    }
#pragma unroll
    for (int h = 0; h < 4; ++h) { bhi[h] = nbhi[h]; blo[h] = nblo[h]; }
    xc0 = nx0; xc1 = nx1;
  }

  // epilogue: per-wave partial of relu(h+b1)@W2 over its 64 cols
  float bvv[4], wvv[4];
#pragma unroll
  for (int h = 0; h < 4; ++h) {
    const int col = (cg * 4 + h) * 16 + lr;
    bvv[h] = b1[col];
    wvv[h] = W2[col];
  }
#pragma unroll
  for (int r = 0; r < 4; ++r) {
    float p = 0.0f;
#pragma unroll
    for (int h = 0; h < 4; ++h)
      p = fmaf(fmaxf(acc[h][r] + bvv[h], 0.0f), wvv[h], p);
#pragma unroll
    for (int off = 1; off < 16; off <<= 1) p += __shfl_xor(p, off, 64);
    if (lr == 0) sred[cg][rg * 16 + lg * 4 + r] = p;
  }
  __syncthreads();
  if (w == 0) {                       // one wave finalizes all 32 rows
    const int row = l & 31;
    const float sc = sred[0][row] + sred[1][row] + b2[0];
    const float wgt = (l < 32) ? __expf(sc) : 0.0f;
    if (l < 32) wlds[row] = wgt;
    float zs = wgt;
#pragma unroll
    for (int off = 1; off < 64; off <<= 1) zs += __shfl_xor(zs, off, 64);
    if (l == 0) atomicAdd(zacc, zs);
  }
  __syncthreads();

  // phase 2: pool own rows (batch sorted); wave w owns 8 rows, lane owns 4 cols
  {
    const int nStart = n0 + w * 8;
    float4 a4 = make_float4(0.f, 0.f, 0.f, 0.f);
    int bprev = batch[nStart];
#pragma unroll 1
    for (int n = nStart; n < nStart + 8; ++n) {
      const int b = batch[n];
      if (b != bprev) {
        float* o = out + (size_t)bprev * D + l * 4;
        atomicAdd(o + 0, a4.x); atomicAdd(o + 1, a4.y);
        atomicAdd(o + 2, a4.z); atomicAdd(o + 3, a4.w);
        a4 = make_float4(0.f, 0.f, 0.f, 0.f);
        bprev = b;
      }
      const float wgt = wlds[n - n0];
      const float4 xv = *reinterpret_cast<const float4*>(x + (size_t)n * D + l * 4);
      a4.x = fmaf(xv.x, wgt, a4.x);
      a4.y = fmaf(xv.y, wgt, a4.y);
      a4.z = fmaf(xv.z, wgt, a4.z);
      a4.w = fmaf(xv.w, wgt, a4.w);
    }
    float* o = out + (size_t)bprev * D + l * 4;
    atomicAdd(o + 0, a4.x); atomicAdd(o + 1, a4.y);
    atomicAdd(o + 2, a4.z); atomicAdd(o + 3, a4.w);
  }
}

// ---- finish: out *= 1/Z ----------------------------------------------------
extern "C" __global__ void __launch_bounds__(256)
k_finish(float* __restrict__ out, const float* __restrict__ zacc, int size)
{
  const int i = blockIdx.x * 256 + threadIdx.x;
  if (i < size) out[i] *= (1.0f / *zacc);
}

extern "C" void kernel_launch(void* const* d_in, const int* in_sizes, int n_in,
                              void* d_out, int out_size, void* d_ws, size_t ws_size,
                              hipStream_t stream)
{
  const float* x     = (const float*)d_in[0];
  const int*   batch = (const int*)d_in[1];
  const float* W1 = (const float*)d_in[3];
  const float* b1 = (const float*)d_in[4];
  const float* W2 = (const float*)d_in[5];
  const float* b2 = (const float*)d_in[6];
  const int N = in_sizes[1];

  float* zacc = (float*)d_ws;
  uint4* phi  = (uint4*)((char*)d_ws + 256);            // 64 KB
  uint4* plo  = (uint4*)((char*)d_ws + 256 + 65536);    // 64 KB

  k_init<<<(out_size + 255) / 256, 256, 0, stream>>>((float*)d_out, out_size, zacc);
  k_pack<<<16, 256, 0, stream>>>(W1, phi, plo);

  const int g1 = (N + BM - 1) / BM;
  k_fused3<<<g1, 256, 0, stream>>>(x, batch, phi, plo, b1, W2, b2,
                                   (float*)d_out, zacc, N);

  k_finish<<<(out_size + 255) / 256, 256, 0, stream>>>((float*)d_out, zacc, out_size);
}